// Round 8
// baseline (1589.037 us; speedup 1.0000x reference)
//
#include <hip/hip_runtime.h>

#define NN 1024
#define NW 32            // u32 words per full 1024-bit row
#define KMAX 640         // max #non-roots supported (binomial(1024,.5): P(K>640)<1e-14)
#define KW 10            // u64 words per compact row (640 bits)
#define KWP 11           // padded LDS row stride (u64) to spread banks
#define INF_KEY 0x7FFFFFFFu

typedef unsigned int u32;
typedef unsigned long long u64;
typedef unsigned short u16;
typedef unsigned char u8;

__device__ __forceinline__ u64 shfl64(u64 v, int src) {
    return (u64)__shfl((long long)v, src);
}

// ---- A0: root hard bits ----
__global__ __launch_bounds__(1024) void root_bits_kernel(
    const float* __restrict__ rp, const float* __restrict__ gr, u32* __restrict__ rootbits)
{
    int tid = threadIdx.x;
    float p = rp[tid];
    float2 g = reinterpret_cast<const float2*>(gr)[tid];
    bool root = (p + g.x) > ((1.0f - p) + g.y);
    u64 m = __ballot(root);
    if ((tid & 31) == 0) rootbits[tid >> 5] = (u32)(m >> (tid & 32));
}

// ---- A1: edge hard bits + root dag rows (full width) ----
__global__ void edge_bits_kernel(const float* __restrict__ ep, const float* __restrict__ ge,
                                 const u32* __restrict__ rootbits,
                                 u32* __restrict__ E, u32* __restrict__ dagbits)
{
    int idx = blockIdx.x * blockDim.x + threadIdx.x;
    int i = idx >> 10;
    float p = ep[idx];
    float2 g = reinterpret_cast<const float2*>(ge)[idx];
    bool hard = (p + g.x) > ((1.0f - p) + g.y);
    u64 m = __ballot(hard);
    int lane = threadIdx.x & 63;
    if ((lane & 31) == 0) {
        int w = idx >> 5;
        u32 hw = (u32)(m >> (lane & 32));
        E[w] = hw;
        int jw = w & 31;
        u32 rootw = rootbits[jw];
        bool rooti = (rootbits[i >> 5] >> (i & 31)) & 1;
        u32 selfm = ((i >> 5) == jw) ? (1u << (i & 31)) : 0u;
        dagbits[w] = rooti ? (hw & ~rootw & ~selfm) : 0u;
    }
}

// ---- AT: 1024x1024 bit transpose ----
__global__ void transpose_bits_kernel(const u32* __restrict__ E, u32* __restrict__ ET)
{
    int hw = (blockIdx.x * blockDim.x + threadIdx.x) >> 5;
    int l = threadIdx.x & 31;
    int R = hw >> 5, C = hw & 31;
    u32 x = E[(R * 32 + l) * NW + C];
    #pragma unroll
    for (int s = 16; s >= 1; s >>= 1) {
        u32 mlo = (s == 16) ? 0x0000FFFFu : (s == 8) ? 0x00FF00FFu :
                  (s == 4) ? 0x0F0F0F0Fu : (s == 2) ? 0x33333333u : 0x55555555u;
        u32 y = __shfl_xor(x, s, 64);
        if ((l & s) == 0) x = (x & mlo) | ((y & mlo) << s);
        else              x = (x & ~mlo) | ((y & ~mlo) >> s);
    }
    ET[(C * 32 + l) * NW + R] = x;
}

// ---- S: compact index tables + seed queue/inq (1 block) ----
__global__ __launch_bounds__(1024) void seed_kernel(
    const u32* __restrict__ ET, const u32* __restrict__ rootbits,
    u32* __restrict__ meta, u16* __restrict__ idx_g, u16* __restrict__ nr_g,
    u32* __restrict__ queue0, u64* __restrict__ inq0)
{
    __shared__ u32 rootm[32], rootpre[32];
    __shared__ u32 key[NN];
    __shared__ u8  inqB[KMAX];
    const int tid = threadIdx.x;
    if (tid < 32) rootm[tid] = rootbits[tid];
    if (tid < KMAX) inqB[tid] = 0;
    __syncthreads();
    if (tid == 0) {
        u32 s = 0;
        #pragma unroll
        for (int w = 0; w < 32; ++w) { rootpre[w] = s; s += __popc(rootm[w]); }
    }
    __syncthreads();

    bool root = (rootm[tid >> 5] >> (tid & 31)) & 1;
    int rbelow = (int)rootpre[tid >> 5] + __popc(rootm[tid >> 5] & ((1u << (tid & 31)) - 1u));
    int nrank = tid - rbelow;
    if (!root) { idx_g[tid] = (u16)nrank; if (nrank < NN) nr_g[nrank] = (u16)tid; }
    else idx_g[tid] = 0xFFFFu;

    // first root hitting tid (scan ET row & rootm)
    int fw = -1; u32 fword = 0;
    {
        const uint4* ET4 = (const uint4*)ET + (size_t)tid * 8;
        const uint4* rm4 = (const uint4*)rootm;
        #pragma unroll
        for (int k = 0; k < 8; ++k) {
            uint4 e = ET4[k], r = rm4[k];
            u32 a0 = e.x & r.x, a1 = e.y & r.y, a2 = e.z & r.z, a3 = e.w & r.w;
            if (fw < 0 && a0) { fw = 4 * k + 0; fword = a0; }
            if (fw < 0 && a1) { fw = 4 * k + 1; fword = a1; }
            if (fw < 0 && a2) { fw = 4 * k + 2; fword = a2; }
            if (fw < 0 && a3) { fw = 4 * k + 3; fword = a3; }
        }
    }
    u32 mykey = INF_KEY;
    if (!root && fw >= 0) {
        int t0 = fw * 32 + __ffs(fword) - 1;
        int rank = (int)rootpre[t0 >> 5] + __popc(rootm[t0 >> 5] & ((1u << (t0 & 31)) - 1u));
        mykey = ((u32)rank << 10) | (u32)tid;
        if (nrank < KMAX) inqB[nrank] = 1;
    }
    key[tid] = mykey;
    __syncthreads();

    int pos = 0, tail = 0;
    {
        const uint4* key4 = (const uint4*)key;
        for (int q = 0; q < 256; ++q) {
            uint4 kk = key4[q];
            pos  += (kk.x < mykey) + (kk.y < mykey) + (kk.z < mykey) + (kk.w < mykey);
            tail += (kk.x != INF_KEY) + (kk.y != INF_KEY) + (kk.z != INF_KEY) + (kk.w != INF_KEY);
        }
    }
    if (mykey != INF_KEY && pos < KMAX) queue0[pos] = (u32)nrank;
    if (tid == 0) {
        u32 R = rootpre[31] + __popc(rootm[31]);
        meta[0] = NN - R;          // K
        meta[1] = (u32)tail;
    }
    __syncthreads();
    if (tid < KW) {
        u64 v = 0;
        #pragma unroll
        for (int b = 0; b < 64; ++b) {
            int a2 = tid * 64 + b;
            v |= ((u64)(a2 < KMAX ? inqB[a2] : 0)) << b;
        }
        inq0[tid] = v;
    }
}

// ---- C: compact E to non-root rows x non-root cols (bit gather) ----
__global__ __launch_bounds__(256) void compactE_kernel(
    const u32* __restrict__ E, const u16* __restrict__ idx_g,
    const u16* __restrict__ nr_g, const u32* __restrict__ meta,
    u64* __restrict__ Ec_g)
{
    __shared__ u16 nrL[NN];
    const int tid = threadIdx.x;
    #pragma unroll
    for (int k = 0; k < 4; ++k) nrL[tid + k * 256] = nr_g[tid + k * 256];
    u32 K = meta[0];
    __syncthreads();
    int gid = blockIdx.x * 256 + tid;        // 0..10239
    int i = gid / KW, w = gid - i * KW;
    if (i >= NN) return;
    u16 a = idx_g[i];
    if (a == 0xFFFFu) return;
    const u32* row = E + i * NW;
    u64 acc = 0;
    int cbase = w * 64;
    for (int b = 0; b < 64; ++b) {
        int c = cbase + b;
        if (c < (int)K) {
            int j = nrL[c];
            acc |= ((u64)((row[j >> 5] >> (j & 31)) & 1u)) << b;
        }
    }
    Ec_g[(u32)a * KW + w] = acc;
}

// ---- B: single-wave sequential BFS on compacted bitsets (no barriers) ----
__global__ __launch_bounds__(64) void bfs_wave(
    u64* __restrict__ Ec_g, const u32* __restrict__ queue0,
    const u64* __restrict__ inq0, const u32* __restrict__ meta,
    u32* __restrict__ procB_g)
{
    extern __shared__ u64 sm64[];
    u64* anc   = sm64;                        // KMAX*KWP
    u64* Ec    = anc + KMAX * KWP;            // KMAX*KWP (becomes dag rows)
    u32* queue = (u32*)(Ec + KMAX * KWP);     // KMAX
    u32* list  = queue + KMAX;                // KMAX
    u8*  procB = (u8*)(list + KMAX);          // KMAX bytes

    const int l = threadIdx.x;
    const u32 K = meta[0];
    u32 tail = meta[1];

    for (int it = l; it < KMAX * KWP; it += 64) { anc[it] = 0; Ec[it] = 0; }
    for (int it = l; it < KMAX; it += 64) procB[it] = 0;
    for (int it = l; it < (int)(K * KW); it += 64) {
        int r = it / KW, w = it - r * KW;
        Ec[r * KWP + w] = Ec_g[it];
    }
    for (int a2 = l; a2 < (int)K; a2 += 64) anc[a2 * KWP + (a2 >> 6)] = 1ull << (a2 & 63);
    for (int it = l; it < (int)tail; it += 64) queue[it] = queue0[it];
    u64 inqw = (l < KW) ? inq0[l] : 0ull;
    __syncthreads();

    if (tail > 0) {
        int head = 0;
        u32 a = queue[0];
        u64 rowE = (l < KW) ? Ec[a * KWP + l] : 0ull;
        u64 rowA = (l < KW) ? anc[a * KWP + l] : 0ull;
        for (;;) {
            u64 hit = rowE & ~rowA;
            u64 newf = hit & ~inqw;
            if (__any(newf != 0ull)) {              // rare: enqueue new nodes (ascending)
                inqw |= hit;
                u64 hw = shfl64(newf, l >> 2);
                u32 ch = (l < 40) ? (u32)((hw >> ((l & 3) << 4)) & 0xFFFFull) : 0u;
                int cnt = __popc(ch);
                int incl = cnt;
                #pragma unroll
                for (int d = 1; d < 64; d <<= 1) { int u = __shfl_up(incl, d); if (l >= d) incl += u; }
                int excl = incl - cnt;
                int tot = __shfl(incl, 63);
                int k2 = (int)tail + excl;
                u32 c2 = ch;
                while (c2) { int b = __ffs(c2) - 1; queue[k2++] = (u32)((l << 4) + b); c2 &= c2 - 1; }
                tail += (u32)tot;
                __syncthreads();
            }
            int hn = head + 1;
            bool last = (hn >= (int)tail);
            u32 qn = last ? 0u : queue[hn];
            u64 rowE_n = (!last && l < KW) ? Ec[qn * KWP + l] : 0ull;   // prefetch
            u64 rowA_n = (!last && l < KW) ? anc[qn * KWP + l] : 0ull;
            if (l < KW) Ec[a * KWP + l] = hit;      // dag row overwrites E row (dead)
            if (l == 0) procB[a] = 1;
            if (last) break;
            {
                // build hit list (compact j indices, ascending)
                u64 hw = shfl64(hit, l >> 2);
                u32 ch = (l < 40) ? (u32)((hw >> ((l & 3) << 4)) & 0xFFFFull) : 0u;
                int cnt = __popc(ch);
                int incl = cnt;
                #pragma unroll
                for (int d = 1; d < 64; d <<= 1) { int u = __shfl_up(incl, d); if (l >= d) incl += u; }
                int excl = incl - cnt;
                int tot = __shfl(incl, 63);
                int k2 = excl;
                u32 c2 = ch;
                while (c2) { int b = __ffs(c2) - 1; list[k2++] = (u32)((l << 4) + b); c2 &= c2 - 1; }
                // scatter: anc[j] |= anc[i] for all hit j (6 rows per pass)
                int g = l / KW;                     // 0..6
                int w = l - g * KW;
                u64 rowAs = shfl64(rowA, w);
                for (int p = 0; p < tot; p += 6) {
                    int slot = p + g;
                    if (g < 6 && slot < tot) {
                        u32 jj = list[slot];
                        anc[jj * KWP + w] |= rowAs;
                    }
                }
            }
            // patch prefetched anc row for this iteration's scatter, advance
            u64 hqw = shfl64(hit, (int)(qn >> 6));
            if ((hqw >> (qn & 63)) & 1ull) rowA_n |= rowA;
            a = qn; rowE = rowE_n; rowA = rowA_n; head = hn;
        }
    }
    __syncthreads();
    for (int it = l; it < (int)(K * KW); it += 64) {
        int r = it / KW, w = it - r * KW;
        Ec_g[it] = Ec[r * KWP + w];
    }
    for (int it = l; it < KMAX / 4; it += 64) procB_g[it] = ((u32*)procB)[it];
}

// ---- F: expand to f32 output directly ----
__global__ __launch_bounds__(256) void final_expand(
    const u32* __restrict__ dagbits, const u64* __restrict__ Ec_g,
    const u16* __restrict__ idx_g, const u32* __restrict__ procB_g,
    const u32* __restrict__ rootbits, float4* __restrict__ out)
{
    int gid = blockIdx.x * 256 + threadIdx.x;    // 262144 threads, 4 elems each
    int i = gid >> 8;
    int j0 = (gid & 255) << 2;
    bool rooti = (rootbits[i >> 5] >> (i & 31)) & 1u;
    float4 o;
    if (rooti) {
        u32 wv = dagbits[i * NW + (j0 >> 5)];
        int sh = j0 & 31;
        o.x = ((wv >> (sh + 0)) & 1u) ? 1.0f : 0.0f;
        o.y = ((wv >> (sh + 1)) & 1u) ? 1.0f : 0.0f;
        o.z = ((wv >> (sh + 2)) & 1u) ? 1.0f : 0.0f;
        o.w = ((wv >> (sh + 3)) & 1u) ? 1.0f : 0.0f;
    } else {
        u32 a = idx_g[i];
        bool pr = ((const u8*)procB_g)[a] != 0;
        float r[4] = {0.f, 0.f, 0.f, 0.f};
        if (pr) {
            u32 rw = rootbits[j0 >> 5];
            const u16* ip = idx_g + j0;
            #pragma unroll
            for (int t = 0; t < 4; ++t) {
                bool rj = (rw >> ((j0 & 31) + t)) & 1u;
                if (!rj) {
                    u32 c = ip[t];
                    u64 wv = Ec_g[a * KW + (c >> 6)];
                    r[t] = ((wv >> (c & 63)) & 1ull) ? 1.0f : 0.0f;
                }
            }
        }
        o.x = r[0]; o.y = r[1]; o.z = r[2]; o.w = r[3];
    }
    out[gid] = o;
}

extern "C" void kernel_launch(void* const* d_in, const int* in_sizes, int n_in,
                              void* d_out, int out_size, void* d_ws, size_t ws_size,
                              hipStream_t stream) {
    const float* root_probs = (const float*)d_in[0];
    const float* edge_probs = (const float*)d_in[1];
    const float* g_roots    = (const float*)d_in[2];
    const float* g_edges    = (const float*)d_in[3];

    char* ws = (char*)d_ws;
    u32* E        = (u32*)(ws);                    // 131072 B
    u32* ET       = (u32*)(ws + 131072);           // 131072 B
    u32* dagbits  = (u32*)(ws + 262144);           // 131072 B
    u32* rootbits = (u32*)(ws + 393216);           // 128 B
    u32* meta     = (u32*)(ws + 393344);           // 32 B
    u32* queue0   = (u32*)(ws + 393376);           // 2560 B
    u64* inq0     = (u64*)(ws + 395936);           // 80 B
    u32* procB_g  = (u32*)(ws + 396016);           // 640 B
    u16* idx_g    = (u16*)(ws + 396656);           // 2048 B
    u16* nr_g     = (u16*)(ws + 398704);           // 2048 B
    u64* Ec_g     = (u64*)(ws + 400752);           // 51200 B

    root_bits_kernel<<<1, NN, 0, stream>>>(root_probs, g_roots, rootbits);
    edge_bits_kernel<<<NN * NN / 256, 256, 0, stream>>>(edge_probs, g_edges, rootbits, E, dagbits);
    transpose_bits_kernel<<<128, 256, 0, stream>>>(E, ET);
    seed_kernel<<<1, NN, 0, stream>>>(ET, rootbits, meta, idx_g, nr_g, queue0, inq0);
    compactE_kernel<<<(NN * KW + 255) / 256, 256, 0, stream>>>(E, idx_g, nr_g, meta, Ec_g);

    size_t lds = (size_t)KMAX * KWP * 8 * 2 + (size_t)KMAX * 4 * 2 + KMAX;
    hipFuncSetAttribute((const void*)bfs_wave,
                        hipFuncAttributeMaxDynamicSharedMemorySize, (int)lds);
    bfs_wave<<<1, 64, lds, stream>>>(Ec_g, queue0, inq0, meta, procB_g);

    final_expand<<<NN * NN / 4 / 256, 256, 0, stream>>>(dagbits, Ec_g, idx_g, procB_g,
                                                        rootbits, (float4*)d_out);
}

// Round 9
// 287.052 us; speedup vs baseline: 5.5357x; 5.5357x over previous
//
#include <hip/hip_runtime.h>

#define NN 1024
#define NW 32            // u32 words per full 1024-bit row
#define KMAX 640         // max #non-roots (P(K>640) < 1e-14)
#define KW 10            // u64 words per compact row
#define KWP 11           // padded LDS row stride (u64)
#define INF_KEY 0x7FFFFFFFu

typedef unsigned int u32;
typedef unsigned long long u64;
typedef unsigned short u16;

__device__ __forceinline__ u64 shfl64(u64 v, int src) {
    return (u64)__shfl((long long)v, src);
}
__device__ __forceinline__ u64 shflxor64(u64 v, int m) {
    return (u64)__shfl_xor((long long)v, m);
}

// ---- A0: root hard bits ----
__global__ __launch_bounds__(1024) void root_bits_kernel(
    const float* __restrict__ rp, const float* __restrict__ gr, u32* __restrict__ rootbits)
{
    int tid = threadIdx.x;
    float p = rp[tid];
    float2 g = reinterpret_cast<const float2*>(gr)[tid];
    bool root = (p + g.x) > ((1.0f - p) + g.y);
    u64 m = __ballot(root);
    if ((tid & 31) == 0) rootbits[tid >> 5] = (u32)(m >> (tid & 32));
}

// ---- A1: edge hard bits + root dag rows (full width) ----
__global__ void edge_bits_kernel(const float* __restrict__ ep, const float* __restrict__ ge,
                                 const u32* __restrict__ rootbits,
                                 u32* __restrict__ E, u32* __restrict__ dagbits)
{
    int idx = blockIdx.x * blockDim.x + threadIdx.x;
    int i = idx >> 10;
    float p = ep[idx];
    float2 g = reinterpret_cast<const float2*>(ge)[idx];
    bool hard = (p + g.x) > ((1.0f - p) + g.y);
    u64 m = __ballot(hard);
    int lane = threadIdx.x & 63;
    if ((lane & 31) == 0) {
        int w = idx >> 5;
        u32 hw = (u32)(m >> (lane & 32));
        E[w] = hw;
        int jw = w & 31;
        u32 rootw = rootbits[jw];
        bool rooti = (rootbits[i >> 5] >> (i & 31)) & 1;
        u32 selfm = ((i >> 5) == jw) ? (1u << (i & 31)) : 0u;
        dagbits[w] = rooti ? (hw & ~rootw & ~selfm) : 0u;
    }
}

// ---- AT: 1024x1024 bit transpose (for seed's in-edge scan) ----
__global__ void transpose_bits_kernel(const u32* __restrict__ E, u32* __restrict__ ET)
{
    int hw = (blockIdx.x * blockDim.x + threadIdx.x) >> 5;
    int l = threadIdx.x & 31;
    int R = hw >> 5, C = hw & 31;
    u32 x = E[(R * 32 + l) * NW + C];
    #pragma unroll
    for (int s = 16; s >= 1; s >>= 1) {
        u32 mlo = (s == 16) ? 0x0000FFFFu : (s == 8) ? 0x00FF00FFu :
                  (s == 4) ? 0x0F0F0F0Fu : (s == 2) ? 0x33333333u : 0x55555555u;
        u32 y = __shfl_xor(x, s, 64);
        if ((l & s) == 0) x = (x & mlo) | ((y & mlo) << s);
        else              x = (x & ~mlo) | ((y & ~mlo) >> s);
    }
    ET[(C * 32 + l) * NW + R] = x;
}

// ---- S: queue-position permutation (posof / nodeofpos) ----
__global__ __launch_bounds__(1024) void seed_kernel(
    const u32* __restrict__ ET, const u32* __restrict__ rootbits,
    u32* __restrict__ meta, u16* __restrict__ posof, u16* __restrict__ nodeofpos)
{
    __shared__ u32 rootm[32], rootpre[32];
    __shared__ u32 key[NN];
    const int tid = threadIdx.x;
    if (tid < 32) rootm[tid] = rootbits[tid];
    __syncthreads();
    if (tid == 0) {
        u32 s = 0;
        #pragma unroll
        for (int w = 0; w < 32; ++w) { rootpre[w] = s; s += __popc(rootm[w]); }
    }
    __syncthreads();

    bool root = (rootm[tid >> 5] >> (tid & 31)) & 1;
    int fw = -1; u32 fword = 0;
    {
        const uint4* ET4 = (const uint4*)ET + (size_t)tid * 8;
        const uint4* rm4 = (const uint4*)rootm;
        #pragma unroll
        for (int k = 0; k < 8; ++k) {
            uint4 e = ET4[k], r = rm4[k];
            u32 a0 = e.x & r.x, a1 = e.y & r.y, a2 = e.z & r.z, a3 = e.w & r.w;
            if (fw < 0 && a0) { fw = 4 * k + 0; fword = a0; }
            if (fw < 0 && a1) { fw = 4 * k + 1; fword = a1; }
            if (fw < 0 && a2) { fw = 4 * k + 2; fword = a2; }
            if (fw < 0 && a3) { fw = 4 * k + 3; fword = a3; }
        }
    }
    u32 mykey = INF_KEY;
    if (!root && fw >= 0) {
        int t0 = fw * 32 + __ffs(fword) - 1;
        int rank = (int)rootpre[t0 >> 5] + __popc(rootm[t0 >> 5] & ((1u << (t0 & 31)) - 1u));
        mykey = ((u32)rank << 10) | (u32)tid;   // (first-hitting-root rank, node) = ref order
    }
    key[tid] = mykey;
    __syncthreads();

    int pos = 0, tail = 0;
    {
        const uint4* key4 = (const uint4*)key;
        for (int q = 0; q < 256; ++q) {
            uint4 kk = key4[q];
            pos  += (kk.x < mykey) + (kk.y < mykey) + (kk.z < mykey) + (kk.w < mykey);
            tail += (kk.x != INF_KEY) + (kk.y != INF_KEY) + (kk.z != INF_KEY) + (kk.w != INF_KEY);
        }
    }
    if (mykey != INF_KEY) { posof[tid] = (u16)pos; if (pos < KMAX) nodeofpos[pos] = (u16)tid; }
    else posof[tid] = 0xFFFFu;
    if (tid == 0) {
        u32 R = rootpre[31] + __popc(rootm[31]);
        meta[0] = NN - R;
        meta[1] = (u32)tail;
    }
}

// ---- C: queue-permuted compact bit matrix Bq[s][t] = E[q_s][q_t] ----
__global__ __launch_bounds__(256) void compactB_kernel(
    const u32* __restrict__ E, const u16* __restrict__ nodeofpos,
    const u32* __restrict__ meta, u64* __restrict__ Bq_g)
{
    __shared__ u16 npL[KMAX];
    const int tid = threadIdx.x;
    for (int k = tid; k < KMAX; k += 256) npL[k] = nodeofpos[k];
    u32 tail = meta[1];
    __syncthreads();
    int gid = blockIdx.x * 256 + tid;        // s*KW + w
    int s = gid / KW, w = gid - s * KW;
    if (s >= (int)tail) return;
    const u32* row = E + (u32)npL[s] * NW;
    u64 acc = 0;
    int cb = w * 64;
    for (int b = 0; b < 64; ++b) {
        int t = cb + b;
        if (t < (int)tail) {
            int j = npL[t];
            acc |= ((u64)((row[j >> 5] >> (j & 31)) & 1u)) << b;
        }
    }
    Bq_g[gid] = acc;
}

// ---- B: blocked sequential closure; wave-0 shfl-serial + all-wave cross propagate ----
__global__ __launch_bounds__(1024) void bfs_blocked(
    u64* __restrict__ Bq_g, const u32* __restrict__ meta)
{
    extern __shared__ u64 sm[];
    u64* A  = sm;                    // KMAX*KWP  (anc rows by queue position)
    u64* Bq = A + KMAX * KWP;        // KMAX*KWP  (edge rows -> dag rows in place)

    const int tid  = threadIdx.x;
    const int lane = tid & 63;
    const int wid  = tid >> 6;
    const u32 tail = meta[1];
    const int nb   = (int)((tail + 63) >> 6);

    for (int it = tid; it < (int)tail * KW; it += 1024) {
        int r = it / KW, w = it - r * KW;
        Bq[r * KWP + w] = Bq_g[it];
    }
    for (int it = tid; it < (int)tail * KWP; it += 1024) {
        int r = it / KWP, w = it - r * KWP;
        A[it] = (w == (r >> 6)) ? (1ull << (r & 63)) : 0ull;
    }
    __syncthreads();

    for (int p = 0; p < nb; ++p) {
        const int b0 = p << 6;
        const int rem = min(64, (int)tail - b0);

        if (wid == 0) {
            const int sp = b0 + lane;
            const bool valid = lane < rem;
            u64 a[KW], b[KW];
            #pragma unroll
            for (int w = 0; w < KW; ++w) {
                a[w] = valid ? A[sp * KWP + w]  : 0ull;
                b[w] = valid ? Bq[sp * KWP + w] : 0ull;
            }
            u64 Dg = 0, ap = 0;
            #pragma unroll
            for (int w = 0; w < KW; ++w) { if (w == p) { Dg = b[w]; ap = a[w]; } }

            for (int s = 0; s < rem; ++s) {
                u64 hl = Dg & ~ap;               // lane's dag word-p candidate
                u64 hrow = shfl64(hl, s);        // = dag row s, block-diagonal word
                bool h = ((hrow >> lane) & 1ull) && (lane > s);
                if (lane == s) {
                    #pragma unroll
                    for (int w = 0; w < KW; ++w) b[w] &= ~a[w];   // finalize dag row
                }
                u64 swp = shfl64(ap, s);
                if (h) ap |= swp;
                #pragma unroll
                for (int w = 0; w < KW; ++w) {
                    u64 sw = shfl64(a[w], s);    // broadcast A_s
                    if (h) a[w] |= sw;
                }
            }
            if (valid) {
                #pragma unroll
                for (int w = 0; w < KW; ++w) {
                    A[sp * KWP + w]  = a[w];
                    Bq[sp * KWP + w] = b[w];
                }
            }
        }
        __syncthreads();

        // cross propagate: A[t] |= OR of A_s over s in block p with hit(s,t), t > block
        const int b1 = b0 + 64;
        if (b1 + (wid << 6) < (int)tail) {       // wave-uniform
            const int t = b1 + tid;
            const int wt = t >> 6;               // wave-uniform word
            u64 x = Bq[(b0 + lane) * KWP + wt];  // dag rows of block p (rem==64 here)
            #pragma unroll
            for (int st = 32; st >= 1; st >>= 1) {
                u64 mlo = (st == 32) ? 0x00000000FFFFFFFFull :
                          (st == 16) ? 0x0000FFFF0000FFFFull :
                          (st == 8)  ? 0x00FF00FF00FF00FFull :
                          (st == 4)  ? 0x0F0F0F0F0F0F0F0Full :
                          (st == 2)  ? 0x3333333333333333ull : 0x5555555555555555ull;
                u64 y = shflxor64(x, st);
                x = ((lane & st) == 0) ? ((x & mlo) | ((y & mlo) << st))
                                       : ((x & ~mlo) | ((y & ~mlo) >> st));
            }
            if (t < (int)tail && x) {            // x = hit column bits (s = 0..63)
                u64 acc[KW];
                #pragma unroll
                for (int w = 0; w < KW; ++w) acc[w] = 0ull;
                u64 m = x;
                while (m) {
                    int s = __ffsll((long long)m) - 1; m &= m - 1;
                    const u64* Ar = A + (size_t)(b0 + s) * KWP;
                    #pragma unroll
                    for (int w = 0; w < KW; ++w) acc[w] |= Ar[w];
                }
                u64* At = A + (size_t)t * KWP;
                #pragma unroll
                for (int w = 0; w < KW; ++w) At[w] |= acc[w];
            }
        }
        __syncthreads();
    }

    for (int it = tid; it < (int)tail * KW; it += 1024) {
        int r = it / KW, w = it - r * KW;
        Bq_g[it] = Bq[r * KWP + w];              // dag rows out (in place)
    }
}

// ---- F: expand to f32 output ----
__global__ __launch_bounds__(256) void final_expand(
    const u32* __restrict__ dagbits, const u64* __restrict__ Bq_g,
    const u16* __restrict__ posof, const u32* __restrict__ meta,
    const u32* __restrict__ rootbits, float4* __restrict__ out)
{
    int gid = blockIdx.x * 256 + threadIdx.x;
    int i = gid >> 8;
    int j0 = (gid & 255) << 2;
    bool rooti = (rootbits[i >> 5] >> (i & 31)) & 1u;
    float4 o;
    if (rooti) {
        u32 wv = dagbits[i * NW + (j0 >> 5)];
        int sh = j0 & 31;
        o.x = ((wv >> (sh + 0)) & 1u) ? 1.0f : 0.0f;
        o.y = ((wv >> (sh + 1)) & 1u) ? 1.0f : 0.0f;
        o.z = ((wv >> (sh + 2)) & 1u) ? 1.0f : 0.0f;
        o.w = ((wv >> (sh + 3)) & 1u) ? 1.0f : 0.0f;
    } else {
        u32 pos = posof[i];
        u32 tail = meta[1];
        float r[4] = {0.f, 0.f, 0.f, 0.f};
        if (pos < tail) {
            const u64* row = Bq_g + (size_t)pos * KW;
            const u16* pj = posof + j0;
            #pragma unroll
            for (int t = 0; t < 4; ++t) {
                u32 pc = pj[t];                  // roots -> 0xFFFF >= tail -> 0
                if (pc < tail) {
                    u64 wv = row[pc >> 6];
                    r[t] = ((wv >> (pc & 63)) & 1ull) ? 1.0f : 0.0f;
                }
            }
        }
        o.x = r[0]; o.y = r[1]; o.z = r[2]; o.w = r[3];
    }
    out[gid] = o;
}

extern "C" void kernel_launch(void* const* d_in, const int* in_sizes, int n_in,
                              void* d_out, int out_size, void* d_ws, size_t ws_size,
                              hipStream_t stream) {
    const float* root_probs = (const float*)d_in[0];
    const float* edge_probs = (const float*)d_in[1];
    const float* g_roots    = (const float*)d_in[2];
    const float* g_edges    = (const float*)d_in[3];

    char* ws = (char*)d_ws;
    u32* E         = (u32*)(ws);                 // 131072 B
    u32* ET        = (u32*)(ws + 131072);        // 131072 B
    u32* dagbits   = (u32*)(ws + 262144);        // 131072 B
    u32* rootbits  = (u32*)(ws + 393216);        // 128 B
    u32* meta      = (u32*)(ws + 393344);        // 64 B
    u16* posof     = (u16*)(ws + 393408);        // 2048 B
    u16* nodeofpos = (u16*)(ws + 395456);        // 1280 B
    u64* Bq_g      = (u64*)(ws + 396800);        // 51200 B

    root_bits_kernel<<<1, NN, 0, stream>>>(root_probs, g_roots, rootbits);
    edge_bits_kernel<<<NN * NN / 256, 256, 0, stream>>>(edge_probs, g_edges, rootbits, E, dagbits);
    transpose_bits_kernel<<<128, 256, 0, stream>>>(E, ET);
    seed_kernel<<<1, NN, 0, stream>>>(ET, rootbits, meta, posof, nodeofpos);
    compactB_kernel<<<(KMAX * KW + 255) / 256, 256, 0, stream>>>(E, nodeofpos, meta, Bq_g);

    size_t lds = (size_t)KMAX * KWP * 8 * 2;     // 112640 B
    hipFuncSetAttribute((const void*)bfs_blocked,
                        hipFuncAttributeMaxDynamicSharedMemorySize, (int)lds);
    bfs_blocked<<<1, NN, lds, stream>>>(Bq_g, meta);

    final_expand<<<NN * NN / 4 / 256, 256, 0, stream>>>(dagbits, Bq_g, posof, meta,
                                                        rootbits, (float4*)d_out);
}

// Round 10
// 202.815 us; speedup vs baseline: 7.8349x; 1.4153x over previous
//
#include <hip/hip_runtime.h>

#define NN 1024
#define NW 32            // u32 words per full 1024-bit row
#define KMAX 640         // max #non-roots (P(K>640) < 1e-14)
#define KW 10            // u64 words per compact row
#define KWP 11           // padded LDS row stride (u64)
#define INF_KEY 0x7FFFFFFFu

typedef unsigned int u32;
typedef unsigned long long u64;
typedef unsigned short u16;

__device__ __forceinline__ u64 shflxor64(u64 v, int m) {
    return (u64)__shfl_xor((long long)v, m);
}
__device__ __forceinline__ u64 rdl64(u64 v, int s) {   // broadcast lane s (uniform s)
    u32 lo = (u32)__builtin_amdgcn_readlane((int)(u32)v, s);
    u32 hi = (u32)__builtin_amdgcn_readlane((int)(u32)(v >> 32), s);
    return ((u64)hi << 32) | (u64)lo;
}
__device__ __forceinline__ u64 transpose64(u64 x, int lane) {
    #pragma unroll
    for (int st = 32; st >= 1; st >>= 1) {
        u64 mlo = (st == 32) ? 0x00000000FFFFFFFFull :
                  (st == 16) ? 0x0000FFFF0000FFFFull :
                  (st == 8)  ? 0x00FF00FF00FF00FFull :
                  (st == 4)  ? 0x0F0F0F0F0F0F0F0Full :
                  (st == 2)  ? 0x3333333333333333ull : 0x5555555555555555ull;
        u64 y = shflxor64(x, st);
        x = ((lane & st) == 0) ? ((x & mlo) | ((y & mlo) << st))
                               : ((x & ~mlo) | ((y & ~mlo) >> st));
    }
    return x;
}

// ---- A0: root hard bits ----
__global__ __launch_bounds__(1024) void root_bits_kernel(
    const float* __restrict__ rp, const float* __restrict__ gr, u32* __restrict__ rootbits)
{
    int tid = threadIdx.x;
    float p = rp[tid];
    float2 g = reinterpret_cast<const float2*>(gr)[tid];
    bool root = (p + g.x) > ((1.0f - p) + g.y);
    u64 m = __ballot(root);
    if ((tid & 31) == 0) rootbits[tid >> 5] = (u32)(m >> (tid & 32));
}

// ---- A1: edge hard bits + root dag rows (full width) ----
__global__ void edge_bits_kernel(const float* __restrict__ ep, const float* __restrict__ ge,
                                 const u32* __restrict__ rootbits,
                                 u32* __restrict__ E, u32* __restrict__ dagbits)
{
    int idx = blockIdx.x * blockDim.x + threadIdx.x;
    int i = idx >> 10;
    float p = ep[idx];
    float2 g = reinterpret_cast<const float2*>(ge)[idx];
    bool hard = (p + g.x) > ((1.0f - p) + g.y);
    u64 m = __ballot(hard);
    int lane = threadIdx.x & 63;
    if ((lane & 31) == 0) {
        int w = idx >> 5;
        u32 hw = (u32)(m >> (lane & 32));
        E[w] = hw;
        int jw = w & 31;
        u32 rootw = rootbits[jw];
        bool rooti = (rootbits[i >> 5] >> (i & 31)) & 1;
        u32 selfm = ((i >> 5) == jw) ? (1u << (i & 31)) : 0u;
        dagbits[w] = rooti ? (hw & ~rootw & ~selfm) : 0u;
    }
}

// ---- AT: 1024x1024 bit transpose (for seed's in-edge scan) ----
__global__ void transpose_bits_kernel(const u32* __restrict__ E, u32* __restrict__ ET)
{
    int hw = (blockIdx.x * blockDim.x + threadIdx.x) >> 5;
    int l = threadIdx.x & 31;
    int R = hw >> 5, C = hw & 31;
    u32 x = E[(R * 32 + l) * NW + C];
    #pragma unroll
    for (int s = 16; s >= 1; s >>= 1) {
        u32 mlo = (s == 16) ? 0x0000FFFFu : (s == 8) ? 0x00FF00FFu :
                  (s == 4) ? 0x0F0F0F0Fu : (s == 2) ? 0x33333333u : 0x55555555u;
        u32 y = __shfl_xor(x, s, 64);
        if ((l & s) == 0) x = (x & mlo) | ((y & mlo) << s);
        else              x = (x & ~mlo) | ((y & ~mlo) >> s);
    }
    ET[(C * 32 + l) * NW + R] = x;
}

// ---- S: queue-position permutation (posof / nodeofpos) ----
__global__ __launch_bounds__(1024) void seed_kernel(
    const u32* __restrict__ ET, const u32* __restrict__ rootbits,
    u32* __restrict__ meta, u16* __restrict__ posof, u16* __restrict__ nodeofpos)
{
    __shared__ u32 rootm[32], rootpre[32];
    __shared__ u32 key[NN];
    const int tid = threadIdx.x;
    if (tid < 32) rootm[tid] = rootbits[tid];
    __syncthreads();
    if (tid == 0) {
        u32 s = 0;
        #pragma unroll
        for (int w = 0; w < 32; ++w) { rootpre[w] = s; s += __popc(rootm[w]); }
    }
    __syncthreads();

    bool root = (rootm[tid >> 5] >> (tid & 31)) & 1;
    int fw = -1; u32 fword = 0;
    {
        const uint4* ET4 = (const uint4*)ET + (size_t)tid * 8;
        const uint4* rm4 = (const uint4*)rootm;
        #pragma unroll
        for (int k = 0; k < 8; ++k) {
            uint4 e = ET4[k], r = rm4[k];
            u32 a0 = e.x & r.x, a1 = e.y & r.y, a2 = e.z & r.z, a3 = e.w & r.w;
            if (fw < 0 && a0) { fw = 4 * k + 0; fword = a0; }
            if (fw < 0 && a1) { fw = 4 * k + 1; fword = a1; }
            if (fw < 0 && a2) { fw = 4 * k + 2; fword = a2; }
            if (fw < 0 && a3) { fw = 4 * k + 3; fword = a3; }
        }
    }
    u32 mykey = INF_KEY;
    if (!root && fw >= 0) {
        int t0 = fw * 32 + __ffs(fword) - 1;
        int rank = (int)rootpre[t0 >> 5] + __popc(rootm[t0 >> 5] & ((1u << (t0 & 31)) - 1u));
        mykey = ((u32)rank << 10) | (u32)tid;   // (first-hitting-root rank, node) = ref order
    }
    key[tid] = mykey;
    __syncthreads();

    int pos = 0, tail = 0;
    {
        const uint4* key4 = (const uint4*)key;
        for (int q = 0; q < 256; ++q) {
            uint4 kk = key4[q];
            pos  += (kk.x < mykey) + (kk.y < mykey) + (kk.z < mykey) + (kk.w < mykey);
            tail += (kk.x != INF_KEY) + (kk.y != INF_KEY) + (kk.z != INF_KEY) + (kk.w != INF_KEY);
        }
    }
    if (mykey != INF_KEY) { posof[tid] = (u16)pos; if (pos < KMAX) nodeofpos[pos] = (u16)tid; }
    else posof[tid] = 0xFFFFu;
    if (tid == 0) {
        u32 R = rootpre[31] + __popc(rootm[31]);
        meta[0] = NN - R;
        meta[1] = (u32)tail;
    }
}

// ---- C: queue-permuted compact bit matrix Bq[s][t] = E[q_s][q_t] ----
__global__ __launch_bounds__(256) void compactB_kernel(
    const u32* __restrict__ E, const u16* __restrict__ nodeofpos,
    const u32* __restrict__ meta, u64* __restrict__ Bq_g)
{
    __shared__ u16 npL[KMAX];
    const int tid = threadIdx.x;
    for (int k = tid; k < KMAX; k += 256) npL[k] = nodeofpos[k];
    u32 tail = meta[1];
    __syncthreads();
    int gid = blockIdx.x * 256 + tid;        // s*KW + w
    int s = gid / KW, w = gid - s * KW;
    if (s >= (int)tail) return;
    const u32* row = E + (u32)npL[s] * NW;
    u64 acc = 0;
    int cb = w * 64;
    for (int b = 0; b < 64; ++b) {
        int t = cb + b;
        if (t < (int)tail) {
            int j = npL[t];
            acc |= ((u64)((row[j >> 5] >> (j & 31)) & 1u)) << b;
        }
    }
    Bq_g[gid] = acc;
}

// ---- B: blocked closure; readlane serial phase overlapped with far cross-propagate ----
__global__ __launch_bounds__(1024) void bfs_blocked(
    u64* __restrict__ Bq_g, const u32* __restrict__ meta)
{
    extern __shared__ u64 sm[];
    u64* A  = sm;                    // KMAX*KWP  (anc rows by queue position)
    u64* Bq = A + KMAX * KWP;        // KMAX*KWP  (edge rows -> dag rows in place)

    const int tid  = threadIdx.x;
    const int lane = tid & 63;
    const int wid  = tid >> 6;
    const u32 tail = meta[1];
    const int nb   = (int)((tail + 63) >> 6);

    for (int it = tid; it < (int)tail * KW; it += 1024) {
        int r = it / KW, w = it - r * KW;
        Bq[r * KWP + w] = Bq_g[it];
    }
    for (int it = tid; it < (int)tail * KWP; it += 1024) {
        int r = it / KWP, w = it - r * KWP;
        A[it] = (w == (r >> 6)) ? (1ull << (r & 63)) : 0ull;
    }
    __syncthreads();

    // serial closure of block p on wave 0 (readlane broadcasts; zero LDS in the chain)
    auto serial_block = [&](int p) {
        const int b0 = p << 6;
        const int rem = min(64, (int)tail - b0);
        const int sp = b0 + lane;
        const bool valid = lane < rem;
        int wph[KW];                                 // reg slot w <-> physical word (w+p)%KW
        #pragma unroll
        for (int w = 0; w < KW; ++w) { int ww = w + p; wph[w] = (ww >= KW) ? ww - KW : ww; }
        u64 a[KW], b[KW];
        #pragma unroll
        for (int w = 0; w < KW; ++w) {
            a[w] = valid ? A[sp * KWP + wph[w]]  : 0ull;
            b[w] = valid ? Bq[sp * KWP + wph[w]] : 0ull;
        }
        const u64 Dg = b[0];                         // word p = slot 0
        #pragma unroll 64
        for (int s = 0; s < 64; ++s) {
            u64 hrow = rdl64(Dg & ~a[0], s);         // dag-candidate row of source s (uniform)
            if (hrow) {
                bool h = (((hrow >> lane) & 1ull) != 0ull) && (lane > s);
                u64 hm = h ? ~0ull : 0ull;
                #pragma unroll
                for (int w = 0; w < KW; ++w) {
                    u64 sw = rdl64(a[w], s);         // A_s broadcast via readlane (SGPR)
                    a[w] |= sw & hm;
                }
            }
        }
        if (valid) {                                 // finalize dag row (a frozen at own step)
            #pragma unroll
            for (int w = 0; w < KW; ++w) {
                A[sp * KWP + wph[w]]  = a[w];
                Bq[sp * KWP + wph[w]] = b[w] & ~a[w];
            }
        }
    };

    // near(ps): sources block ps -> targets block ps+1; waves 0..KW-1 (one word each)
    auto near_cross = [&](int ps) {
        const int sb0 = ps << 6;
        const int b0t = sb0 + 64;
        if (wid < KW && b0t < (int)tail) {
            const int wt = b0t >> 6;
            u64 x = transpose64(Bq[(sb0 + lane) * KWP + wt], lane);
            int t = b0t + lane;
            if (t < (int)tail && x) {
                u64 acc = 0, m = x;
                while (m) {
                    int s = __ffsll((long long)m) - 1; m &= m - 1;
                    acc |= A[(sb0 + s) * KWP + wid];
                }
                A[t * KWP + wid] |= acc;
            }
        }
    };

    // far(ps): sources block ps -> targets [sb0+128, tail); waves 1..15, lane = target
    auto far_cross = [&](int ps) {
        const int sb0 = ps << 6;
        const int t0 = sb0 + 128 + ((wid - 1) << 6);
        if (t0 < (int)tail) {
            const int wt = t0 >> 6;
            u64 x = transpose64(Bq[(sb0 + lane) * KWP + wt], lane);
            int t = t0 + lane;
            if (t < (int)tail && x) {
                u64 acc[KW];
                #pragma unroll
                for (int w = 0; w < KW; ++w) acc[w] = 0ull;
                u64 m = x;
                while (m) {
                    int s = __ffsll((long long)m) - 1; m &= m - 1;
                    const u64* Ar = A + (size_t)(sb0 + s) * KWP;
                    #pragma unroll
                    for (int w = 0; w < KW; ++w) acc[w] |= Ar[w];
                }
                u64* At = A + (size_t)t * KWP;
                #pragma unroll
                for (int w = 0; w < KW; ++w) At[w] |= acc[w];
            }
        }
    };

    if (nb > 0) {
        if (wid == 0) serial_block(0);
        __syncthreads();
        for (int p = 1; p < nb; ++p) {
            near_cross(p - 1);                       // sources p-1 -> block p
            __syncthreads();
            if (wid == 0) serial_block(p);           // block p  (A[block p] complete)
            else          far_cross(p - 1);          // sources p-1 -> blocks >= p+1
            __syncthreads();
        }
    }

    for (int it = tid; it < (int)tail * KW; it += 1024) {
        int r = it / KW, w = it - r * KW;
        Bq_g[it] = Bq[r * KWP + w];                  // dag rows out (in place)
    }
}

// ---- F: expand to f32 output ----
__global__ __launch_bounds__(256) void final_expand(
    const u32* __restrict__ dagbits, const u64* __restrict__ Bq_g,
    const u16* __restrict__ posof, const u32* __restrict__ meta,
    const u32* __restrict__ rootbits, float4* __restrict__ out)
{
    int gid = blockIdx.x * 256 + threadIdx.x;
    int i = gid >> 8;
    int j0 = (gid & 255) << 2;
    bool rooti = (rootbits[i >> 5] >> (i & 31)) & 1u;
    float4 o;
    if (rooti) {
        u32 wv = dagbits[i * NW + (j0 >> 5)];
        int sh = j0 & 31;
        o.x = ((wv >> (sh + 0)) & 1u) ? 1.0f : 0.0f;
        o.y = ((wv >> (sh + 1)) & 1u) ? 1.0f : 0.0f;
        o.z = ((wv >> (sh + 2)) & 1u) ? 1.0f : 0.0f;
        o.w = ((wv >> (sh + 3)) & 1u) ? 1.0f : 0.0f;
    } else {
        u32 pos = posof[i];
        u32 tail = meta[1];
        float r[4] = {0.f, 0.f, 0.f, 0.f};
        if (pos < tail) {
            const u64* row = Bq_g + (size_t)pos * KW;
            const u16* pj = posof + j0;
            #pragma unroll
            for (int t = 0; t < 4; ++t) {
                u32 pc = pj[t];                  // roots -> 0xFFFF >= tail -> 0
                if (pc < tail) {
                    u64 wv = row[pc >> 6];
                    r[t] = ((wv >> (pc & 63)) & 1ull) ? 1.0f : 0.0f;
                }
            }
        }
        o.x = r[0]; o.y = r[1]; o.z = r[2]; o.w = r[3];
    }
    out[gid] = o;
}

extern "C" void kernel_launch(void* const* d_in, const int* in_sizes, int n_in,
                              void* d_out, int out_size, void* d_ws, size_t ws_size,
                              hipStream_t stream) {
    const float* root_probs = (const float*)d_in[0];
    const float* edge_probs = (const float*)d_in[1];
    const float* g_roots    = (const float*)d_in[2];
    const float* g_edges    = (const float*)d_in[3];

    char* ws = (char*)d_ws;
    u32* E         = (u32*)(ws);                 // 131072 B
    u32* ET        = (u32*)(ws + 131072);        // 131072 B
    u32* dagbits   = (u32*)(ws + 262144);        // 131072 B
    u32* rootbits  = (u32*)(ws + 393216);        // 128 B
    u32* meta      = (u32*)(ws + 393344);        // 64 B
    u16* posof     = (u16*)(ws + 393408);        // 2048 B
    u16* nodeofpos = (u16*)(ws + 395456);        // 1280 B
    u64* Bq_g      = (u64*)(ws + 396800);        // 51200 B

    root_bits_kernel<<<1, NN, 0, stream>>>(root_probs, g_roots, rootbits);
    edge_bits_kernel<<<NN * NN / 256, 256, 0, stream>>>(edge_probs, g_edges, rootbits, E, dagbits);
    transpose_bits_kernel<<<128, 256, 0, stream>>>(E, ET);
    seed_kernel<<<1, NN, 0, stream>>>(ET, rootbits, meta, posof, nodeofpos);
    compactB_kernel<<<(KMAX * KW + 255) / 256, 256, 0, stream>>>(E, nodeofpos, meta, Bq_g);

    size_t lds = (size_t)KMAX * KWP * 8 * 2;     // 112640 B
    hipFuncSetAttribute((const void*)bfs_blocked,
                        hipFuncAttributeMaxDynamicSharedMemorySize, (int)lds);
    bfs_blocked<<<1, NN, lds, stream>>>(Bq_g, meta);

    final_expand<<<NN * NN / 4 / 256, 256, 0, stream>>>(dagbits, Bq_g, posof, meta,
                                                        rootbits, (float4*)d_out);
}